// Round 2
// baseline (5470.738 us; speedup 1.0000x reference)
//
#include <hip/hip_runtime.h>

#define T_STEPS 512
#define D_IN    64
#define BC      2      // batch columns per block
#define NW      64     // max per-thread weight floats
#define BLOCK   512

// ---------------------------------------------------------------------------
// Layer-skewed pipeline: at tick tau, layer l computes timestep t = tau - l,
// out-proj computes t = tau - 5. All sections within a tick are independent
// (read states written last tick) -> 2 barriers per tick instead of 11.
//
// Section table (G phase, all concurrent, disjoint tid ranges):
//   sec  role  G   K  klen kc  thr  tid-range  gbase  input
//   s0   ih0   96  64  16   4   96    0-95       0    inv (x)
//   s1   hh0   96  32   8   4   96   96-191     96    hbuf[0]
//   s9   hh4   96  32  16   2   48  192-239    528    hbuf[4]
//   s2   ih1   48  32   8   4   48  240-287    192    hbuf[0]
//   s3   hh1   48  16   8   2   24  288-311    240    hbuf[1]
//   s7   hh3   48  16   8   2   24  312-335    384    hbuf[3]
//   s8   ih4   96  16   8   2   48  336-383    432    hbuf[3]
//   s10  out   64  32   8   4   64  384-447     --    hbuf[4] -> global
//   s4   ih2   24  16   8   2   12  448-459    288    hbuf[1]
//   s5   hh2   24   8   8   1    6  460-465    312    hbuf[2]
//   s6   ih3   48   8   8   1   12  466-477    336    hbuf[2]
//   x-prefetch: tid 480-511 (32 thr x float4 = 128 floats = x tile)
// Section starts are multiples of KC (butterfly groups never straddle waves).
// Gate rows: gi0:0 gh0:96 gi1:192 gh1:240 gi2:288 gh2:312 gi3:336 gh3:384
//            gi4:432 gh4:528  (624 rows x BC floats)
// ---------------------------------------------------------------------------

__device__ __forceinline__ float sigmoid_f(float x) {
    return 1.0f / (1.0f + __expf(-x));
}
__device__ __forceinline__ float tanh_f(float x) {
    return 1.0f - 2.0f / (__expf(2.0f * x) + 1.0f);
}

// ROT: k-rotation per kci to break same-bank broadcast strides (only needed
// where KLEN*BC is a multiple of 32 floats AND KC>2; here: s0).
template<int KLEN, int KC, int ROT>
__device__ __forceinline__ void load_sec(float (&wr)[NW], float (&bs)[4], int local,
                                         const float* __restrict__ W,
                                         const float* __restrict__ bv, int K)
{
    const int gb = local / KC, kci = local % KC;
    const int g0 = gb * 4, k0 = kci * KLEN;
    const int start = (ROT * kci) & (KLEN - 1);
#pragma unroll
    for (int j = 0; j < 4; ++j) {
#pragma unroll
        for (int kk = 0; kk < KLEN; ++kk) {
            const int ke = k0 + ((kk + start) & (KLEN - 1));
            wr[j * KLEN + kk] = W[(g0 + j) * K + ke];
        }
        bs[j] = bv[g0 + j];
    }
}

template<int KLEN, int KC, int ROT>
__device__ __forceinline__ void gemm_sec(const float (&wr)[NW], const float (&bs)[4],
                                         int local, const float* __restrict__ inv,
                                         float* __restrict__ gate, int gbase)
{
    const int gb = local / KC, kci = local % KC;
    const int g0 = gb * 4, k0 = kci * KLEN;
    const int start = (ROT * kci) & (KLEN - 1);
    float acc[4][BC];
#pragma unroll
    for (int j = 0; j < 4; ++j) {
        const float bj = (kci == 0) ? bs[j] : 0.0f;
        acc[j][0] = bj; acc[j][1] = bj;
    }
#pragma unroll
    for (int kk = 0; kk < KLEN; ++kk) {
        const int ke = k0 + ((kk + start) & (KLEN - 1));
        const float2 v = *(const float2*)&inv[ke * BC];
#pragma unroll
        for (int j = 0; j < 4; ++j) {
            const float w = wr[j * KLEN + kk];
            acc[j][0] = fmaf(w, v.x, acc[j][0]);
            acc[j][1] = fmaf(w, v.y, acc[j][1]);
        }
    }
#pragma unroll
    for (int m = 1; m < KC; m <<= 1)
#pragma unroll
        for (int j = 0; j < 4; ++j) {
            acc[j][0] += __shfl_xor(acc[j][0], m, 64);
            acc[j][1] += __shfl_xor(acc[j][1], m, 64);
        }
    if (kci == 0) {
#pragma unroll
        for (int j = 0; j < 4; ++j) {
            float2 o = {acc[j][0], acc[j][1]};
            *(float2*)&gate[(gbase + g0 + j) * BC] = o;
        }
    }
}

template<int KLEN, int KC>
__device__ __forceinline__ void out_sec(const float (&wr)[NW], const float (&bs)[4],
                                        int local, const float* __restrict__ inv,
                                        float* __restrict__ outp /* = out + (b0*T + t)*64 */)
{
    const int gb = local / KC, kci = local % KC;
    const int g0 = gb * 4, k0 = kci * KLEN;
    float acc[4][BC];
#pragma unroll
    for (int j = 0; j < 4; ++j) {
        const float bj = (kci == 0) ? bs[j] : 0.0f;
        acc[j][0] = bj; acc[j][1] = bj;
    }
#pragma unroll
    for (int kk = 0; kk < KLEN; ++kk) {
        const float2 v = *(const float2*)&inv[(k0 + kk) * BC];
#pragma unroll
        for (int j = 0; j < 4; ++j) {
            const float w = wr[j * KLEN + kk];
            acc[j][0] = fmaf(w, v.x, acc[j][0]);
            acc[j][1] = fmaf(w, v.y, acc[j][1]);
        }
    }
#pragma unroll
    for (int m = 1; m < KC; m <<= 1)
#pragma unroll
        for (int j = 0; j < 4; ++j) {
            acc[j][0] += __shfl_xor(acc[j][0], m, 64);
            acc[j][1] += __shfl_xor(acc[j][1], m, 64);
        }
    if (kci == 0) {
#pragma unroll
        for (int b = 0; b < BC; ++b) {
            float4 o = {acc[0][b], acc[1][b], acc[2][b], acc[3][b]};
            *(float4*)&outp[(size_t)b * (T_STEPS * 64) + g0] = o;
        }
    }
}

__device__ __forceinline__ void upd(int H, float* __restrict__ hrow, int local,
                                    const float* __restrict__ gate, int ihb, int hhb)
{
    const int h = local >> 1, b = local & 1;
    const float ir  = gate[(ihb + h) * BC + b];
    const float hr  = gate[(hhb + h) * BC + b];
    const float iz  = gate[(ihb + H + h) * BC + b];
    const float hz  = gate[(hhb + H + h) * BC + b];
    const float in_ = gate[(ihb + 2 * H + h) * BC + b];
    const float hn  = gate[(hhb + 2 * H + h) * BC + b];
    const float r = sigmoid_f(ir + hr);
    const float z = sigmoid_f(iz + hz);
    const float n = tanh_f(in_ + r * hn);
    hrow[h * BC + b] = (1.0f - z) * n + z * hrow[h * BC + b];
}

__global__ __launch_bounds__(BLOCK, 4)
void gru_kernel(const float* __restrict__ X,
                const float* wih0, const float* whh0, const float* bih0, const float* bhh0,
                const float* wih1, const float* whh1, const float* bih1, const float* bhh1,
                const float* wih2, const float* whh2, const float* bih2, const float* bhh2,
                const float* wih3, const float* whh3, const float* bih3, const float* bhh3,
                const float* wih4, const float* whh4, const float* bih4, const float* bhh4,
                const float* wout, const float* bout,
                float* __restrict__ out)
{
    __shared__ __align__(16) float inv0[D_IN * BC];    // x(tau) tile [d][b]
    __shared__ __align__(16) float hbuf[5][32 * BC];   // h states [l][h][b]
    __shared__ __align__(16) float gate[624 * BC];     // gate partials [row][b]

    const int tid = threadIdx.x;
    const int b0  = blockIdx.x * BC;

    float wr[NW];
    float bs[4];

    // ---- startup: per-thread weight slices into registers (one section each) ----
    if      (tid < 96)  load_sec<16, 4, 4>(wr, bs, tid,       wih0, bih0, 64);  // s0
    else if (tid < 192) load_sec< 8, 4, 0>(wr, bs, tid - 96,  whh0, bhh0, 32);  // s1
    else if (tid < 240) load_sec<16, 2, 0>(wr, bs, tid - 192, whh4, bhh4, 32);  // s9
    else if (tid < 288) load_sec< 8, 4, 0>(wr, bs, tid - 240, wih1, bih1, 32);  // s2
    else if (tid < 312) load_sec< 8, 2, 0>(wr, bs, tid - 288, whh1, bhh1, 16);  // s3
    else if (tid < 336) load_sec< 8, 2, 0>(wr, bs, tid - 312, whh3, bhh3, 16);  // s7
    else if (tid < 384) load_sec< 8, 2, 0>(wr, bs, tid - 336, wih4, bih4, 16);  // s8
    else if (tid < 448) load_sec< 8, 4, 0>(wr, bs, tid - 384, wout, bout, 32);  // s10
    else if (tid < 460) load_sec< 8, 2, 0>(wr, bs, tid - 448, wih2, bih2, 16);  // s4
    else if (tid < 466) load_sec< 8, 1, 0>(wr, bs, tid - 460, whh2, bhh2, 8);   // s5
    else if (tid < 478) load_sec< 8, 1, 0>(wr, bs, tid - 466, wih3, bih3, 8);   // s6

    // ---- zero states, stage x(0) ----
    for (int i = tid; i < 5 * 32 * BC; i += BLOCK) ((float*)hbuf)[i] = 0.0f;
    if (tid >= 480) {
        const int e = tid - 480, b = e >> 4, d0 = (e & 15) << 2;
        const float4 v = *(const float4*)&X[(size_t)(b0 + b) * (T_STEPS * D_IN) + d0];
        inv0[(d0 + 0) * BC + b] = v.x; inv0[(d0 + 1) * BC + b] = v.y;
        inv0[(d0 + 2) * BC + b] = v.z; inv0[(d0 + 3) * BC + b] = v.w;
    }
    __syncthreads();

    float4 xr = {0.f, 0.f, 0.f, 0.f};

    for (int tau = 0; tau < T_STEPS + 5; ++tau) {
        // ================= G phase: all gemms concurrent =================
        if (tid < 96) {
            if (tau < 512)              gemm_sec<16, 4, 4>(wr, bs, tid,       inv0,    gate, 0);
        } else if (tid < 192) {
            if (tau < 512)              gemm_sec< 8, 4, 0>(wr, bs, tid - 96,  hbuf[0], gate, 96);
        } else if (tid < 240) {
            if (tau >= 4 && tau <= 515) gemm_sec<16, 2, 0>(wr, bs, tid - 192, hbuf[4], gate, 528);
        } else if (tid < 288) {
            if (tau >= 1 && tau <= 512) gemm_sec< 8, 4, 0>(wr, bs, tid - 240, hbuf[0], gate, 192);
        } else if (tid < 312) {
            if (tau >= 1 && tau <= 512) gemm_sec< 8, 2, 0>(wr, bs, tid - 288, hbuf[1], gate, 240);
        } else if (tid < 336) {
            if (tau >= 3 && tau <= 514) gemm_sec< 8, 2, 0>(wr, bs, tid - 312, hbuf[3], gate, 384);
        } else if (tid < 384) {
            if (tau >= 4 && tau <= 515) gemm_sec< 8, 2, 0>(wr, bs, tid - 336, hbuf[3], gate, 432);
        } else if (tid < 448) {
            if (tau >= 5)               out_sec< 8, 4>(wr, bs, tid - 384, hbuf[4],
                                            out + ((size_t)b0 * T_STEPS + (tau - 5)) * 64);
        } else if (tid < 460) {
            if (tau >= 2 && tau <= 513) gemm_sec< 8, 2, 0>(wr, bs, tid - 448, hbuf[1], gate, 288);
        } else if (tid < 466) {
            if (tau >= 2 && tau <= 513) gemm_sec< 8, 1, 0>(wr, bs, tid - 460, hbuf[2], gate, 312);
        } else if (tid < 478) {
            if (tau >= 3 && tau <= 514) gemm_sec< 8, 1, 0>(wr, bs, tid - 466, hbuf[2], gate, 336);
        } else if (tid >= 480) {
            if (tau + 1 < T_STEPS) {    // prefetch x(tau+1) into registers
                const int e = tid - 480, b = e >> 4, d0 = (e & 15) << 2;
                xr = *(const float4*)&X[((size_t)(b0 + b) * T_STEPS + (tau + 1)) * D_IN + d0];
            }
        }
        __syncthreads();
        // ================= U phase: all layer updates concurrent =================
        if (tid < 64) {
            if (tau < 512)              upd(32, hbuf[0], tid,       gate, 0,   96);
        } else if (tid < 96) {
            if (tau >= 1 && tau <= 512) upd(16, hbuf[1], tid - 64,  gate, 192, 240);
        } else if (tid < 112) {
            if (tau >= 2 && tau <= 513) upd(8,  hbuf[2], tid - 96,  gate, 288, 312);
        } else if (tid < 144) {
            if (tau >= 3 && tau <= 514) upd(16, hbuf[3], tid - 112, gate, 336, 384);
        } else if (tid < 208) {
            if (tau >= 4 && tau <= 515) upd(32, hbuf[4], tid - 144, gate, 432, 528);
        } else if (tid >= 480) {
            if (tau + 1 < T_STEPS) {    // commit x(tau+1) to LDS
                const int e = tid - 480, b = e >> 4, d0 = (e & 15) << 2;
                inv0[(d0 + 0) * BC + b] = xr.x; inv0[(d0 + 1) * BC + b] = xr.y;
                inv0[(d0 + 2) * BC + b] = xr.z; inv0[(d0 + 3) * BC + b] = xr.w;
            }
        }
        __syncthreads();
    }
}

extern "C" void kernel_launch(void* const* d_in, const int* in_sizes, int n_in,
                              void* d_out, int out_size, void* d_ws, size_t ws_size,
                              hipStream_t stream)
{
    const float* X = (const float*)d_in[0];
    const float* wih[5]; const float* whh[5]; const float* bih[5]; const float* bhh[5];
    for (int l = 0; l < 5; ++l) {
        wih[l] = (const float*)d_in[1 + 4 * l];
        whh[l] = (const float*)d_in[2 + 4 * l];
        bih[l] = (const float*)d_in[3 + 4 * l];
        bhh[l] = (const float*)d_in[4 + 4 * l];
    }
    const float* wout = (const float*)d_in[21];
    const float* bout = (const float*)d_in[22];

    gru_kernel<<<1024 / BC, BLOCK, 0, stream>>>(
        X,
        wih[0], whh[0], bih[0], bhh[0],
        wih[1], whh[1], bih[1], bhh[1],
        wih[2], whh[2], bih[2], bhh[2],
        wih[3], whh[3], bih[3], bhh[3],
        wih[4], whh[4], bih[4], bhh[4],
        wout, bout,
        (float*)d_out);
}

// Round 3
// 2034.856 us; speedup vs baseline: 2.6885x; 2.6885x over previous
//
#include <hip/hip_runtime.h>

#define T_STEPS 512
#define D_IN    64
#define BC      2      // batch columns per block
#define NW      64     // max per-thread weight floats
#define BLOCK   512

// ---------------------------------------------------------------------------
// Layer-skewed pipeline: at tick tau, layer l computes timestep t = tau - l,
// out-proj computes t = tau - 5. All sections within a tick are independent
// (read states written last tick) -> 2 barriers per tick instead of 11.
//
// __launch_bounds__(512, 2): 128-VGPR cap. (512,4) forced a 64-VGPR cap which
// SPILLED the per-thread weight registers to scratch -> 3.7 GB HBM traffic
// (R2 post-mortem). 2 blocks/CU is the max that keeps weights in registers.
//
// Section table (G phase, all concurrent, disjoint tid ranges):
//   sec  role  G   K  klen kc  thr  tid-range  gbase  input
//   s0   ih0   96  64  16   4   96    0-95       0    inv (x)
//   s1   hh0   96  32   8   4   96   96-191     96    hbuf[0]
//   s9   hh4   96  32  16   2   48  192-239    528    hbuf[4]
//   s2   ih1   48  32   8   4   48  240-287    192    hbuf[0]
//   s3   hh1   48  16   8   2   24  288-311    240    hbuf[1]
//   s7   hh3   48  16   8   2   24  312-335    384    hbuf[3]
//   s8   ih4   96  16   8   2   48  336-383    432    hbuf[3]
//   s10  out   64  32   8   4   64  384-447     --    hbuf[4] -> global
//   s4   ih2   24  16   8   2   12  448-459    288    hbuf[1]
//   s5   hh2   24   8   8   1    6  460-465    312    hbuf[2]
//   s6   ih3   48   8   8   1   12  466-477    336    hbuf[2]
//   x-prefetch: tid 480-511 (32 thr x float4 = 128 floats = x tile)
// Section starts are multiples of KC (butterfly groups never straddle waves).
// Gate rows: gi0:0 gh0:96 gi1:192 gh1:240 gi2:288 gh2:312 gi3:336 gh3:384
//            gi4:432 gh4:528  (624 rows x BC floats)
// ---------------------------------------------------------------------------

__device__ __forceinline__ float sigmoid_f(float x) {
    return 1.0f / (1.0f + __expf(-x));
}
__device__ __forceinline__ float tanh_f(float x) {
    return 1.0f - 2.0f / (__expf(2.0f * x) + 1.0f);
}

// ROT: k-rotation per kci to break same-bank broadcast strides (only needed
// where KLEN*BC is a multiple of 32 floats AND KC>2; here: s0).
template<int KLEN, int KC, int ROT>
__device__ __forceinline__ void load_sec(float (&wr)[NW], float (&bs)[4], int local,
                                         const float* __restrict__ W,
                                         const float* __restrict__ bv, int K)
{
    const int gb = local / KC, kci = local % KC;
    const int g0 = gb * 4, k0 = kci * KLEN;
    const int start = (ROT * kci) & (KLEN - 1);
#pragma unroll
    for (int j = 0; j < 4; ++j) {
#pragma unroll
        for (int kk = 0; kk < KLEN; ++kk) {
            const int ke = k0 + ((kk + start) & (KLEN - 1));
            wr[j * KLEN + kk] = W[(g0 + j) * K + ke];
        }
        bs[j] = bv[g0 + j];
    }
}

template<int KLEN, int KC, int ROT>
__device__ __forceinline__ void gemm_sec(const float (&wr)[NW], const float (&bs)[4],
                                         int local, const float* __restrict__ inv,
                                         float* __restrict__ gate, int gbase)
{
    const int gb = local / KC, kci = local % KC;
    const int g0 = gb * 4, k0 = kci * KLEN;
    const int start = (ROT * kci) & (KLEN - 1);
    float acc[4][BC];
#pragma unroll
    for (int j = 0; j < 4; ++j) {
        const float bj = (kci == 0) ? bs[j] : 0.0f;
        acc[j][0] = bj; acc[j][1] = bj;
    }
#pragma unroll
    for (int kk = 0; kk < KLEN; ++kk) {
        const int ke = k0 + ((kk + start) & (KLEN - 1));
        const float2 v = *(const float2*)&inv[ke * BC];
#pragma unroll
        for (int j = 0; j < 4; ++j) {
            const float w = wr[j * KLEN + kk];
            acc[j][0] = fmaf(w, v.x, acc[j][0]);
            acc[j][1] = fmaf(w, v.y, acc[j][1]);
        }
    }
#pragma unroll
    for (int m = 1; m < KC; m <<= 1)
#pragma unroll
        for (int j = 0; j < 4; ++j) {
            acc[j][0] += __shfl_xor(acc[j][0], m, 64);
            acc[j][1] += __shfl_xor(acc[j][1], m, 64);
        }
    if (kci == 0) {
#pragma unroll
        for (int j = 0; j < 4; ++j) {
            float2 o = {acc[j][0], acc[j][1]};
            *(float2*)&gate[(gbase + g0 + j) * BC] = o;
        }
    }
}

template<int KLEN, int KC>
__device__ __forceinline__ void out_sec(const float (&wr)[NW], const float (&bs)[4],
                                        int local, const float* __restrict__ inv,
                                        float* __restrict__ outp /* = out + (b0*T + t)*64 */)
{
    const int gb = local / KC, kci = local % KC;
    const int g0 = gb * 4, k0 = kci * KLEN;
    float acc[4][BC];
#pragma unroll
    for (int j = 0; j < 4; ++j) {
        const float bj = (kci == 0) ? bs[j] : 0.0f;
        acc[j][0] = bj; acc[j][1] = bj;
    }
#pragma unroll
    for (int kk = 0; kk < KLEN; ++kk) {
        const float2 v = *(const float2*)&inv[(k0 + kk) * BC];
#pragma unroll
        for (int j = 0; j < 4; ++j) {
            const float w = wr[j * KLEN + kk];
            acc[j][0] = fmaf(w, v.x, acc[j][0]);
            acc[j][1] = fmaf(w, v.y, acc[j][1]);
        }
    }
#pragma unroll
    for (int m = 1; m < KC; m <<= 1)
#pragma unroll
        for (int j = 0; j < 4; ++j) {
            acc[j][0] += __shfl_xor(acc[j][0], m, 64);
            acc[j][1] += __shfl_xor(acc[j][1], m, 64);
        }
    if (kci == 0) {
#pragma unroll
        for (int b = 0; b < BC; ++b) {
            float4 o = {acc[0][b], acc[1][b], acc[2][b], acc[3][b]};
            *(float4*)&outp[(size_t)b * (T_STEPS * 64) + g0] = o;
        }
    }
}

__device__ __forceinline__ void upd(int H, float* __restrict__ hrow, int local,
                                    const float* __restrict__ gate, int ihb, int hhb)
{
    const int h = local >> 1, b = local & 1;
    const float ir  = gate[(ihb + h) * BC + b];
    const float hr  = gate[(hhb + h) * BC + b];
    const float iz  = gate[(ihb + H + h) * BC + b];
    const float hz  = gate[(hhb + H + h) * BC + b];
    const float in_ = gate[(ihb + 2 * H + h) * BC + b];
    const float hn  = gate[(hhb + 2 * H + h) * BC + b];
    const float r = sigmoid_f(ir + hr);
    const float z = sigmoid_f(iz + hz);
    const float n = tanh_f(in_ + r * hn);
    hrow[h * BC + b] = (1.0f - z) * n + z * hrow[h * BC + b];
}

__global__ __launch_bounds__(BLOCK, 2)
void gru_kernel(const float* __restrict__ X,
                const float* wih0, const float* whh0, const float* bih0, const float* bhh0,
                const float* wih1, const float* whh1, const float* bih1, const float* bhh1,
                const float* wih2, const float* whh2, const float* bih2, const float* bhh2,
                const float* wih3, const float* whh3, const float* bih3, const float* bhh3,
                const float* wih4, const float* whh4, const float* bih4, const float* bhh4,
                const float* wout, const float* bout,
                float* __restrict__ out)
{
    __shared__ __align__(16) float inv0[D_IN * BC];    // x(tau) tile [d][b]
    __shared__ __align__(16) float hbuf[5][32 * BC];   // h states [l][h][b]
    __shared__ __align__(16) float gate[624 * BC];     // gate partials [row][b]

    const int tid = threadIdx.x;
    const int b0  = blockIdx.x * BC;

    float wr[NW];
    float bs[4];

    // ---- startup: per-thread weight slices into registers (one section each) ----
    if      (tid < 96)  load_sec<16, 4, 4>(wr, bs, tid,       wih0, bih0, 64);  // s0
    else if (tid < 192) load_sec< 8, 4, 0>(wr, bs, tid - 96,  whh0, bhh0, 32);  // s1
    else if (tid < 240) load_sec<16, 2, 0>(wr, bs, tid - 192, whh4, bhh4, 32);  // s9
    else if (tid < 288) load_sec< 8, 4, 0>(wr, bs, tid - 240, wih1, bih1, 32);  // s2
    else if (tid < 312) load_sec< 8, 2, 0>(wr, bs, tid - 288, whh1, bhh1, 16);  // s3
    else if (tid < 336) load_sec< 8, 2, 0>(wr, bs, tid - 312, whh3, bhh3, 16);  // s7
    else if (tid < 384) load_sec< 8, 2, 0>(wr, bs, tid - 336, wih4, bih4, 16);  // s8
    else if (tid < 448) load_sec< 8, 4, 0>(wr, bs, tid - 384, wout, bout, 32);  // s10
    else if (tid < 460) load_sec< 8, 2, 0>(wr, bs, tid - 448, wih2, bih2, 16);  // s4
    else if (tid < 466) load_sec< 8, 1, 0>(wr, bs, tid - 460, whh2, bhh2, 8);   // s5
    else if (tid < 478) load_sec< 8, 1, 0>(wr, bs, tid - 466, wih3, bih3, 8);   // s6

    // ---- zero states, stage x(0) ----
    for (int i = tid; i < 5 * 32 * BC; i += BLOCK) ((float*)hbuf)[i] = 0.0f;
    if (tid >= 480) {
        const int e = tid - 480, b = e >> 4, d0 = (e & 15) << 2;
        const float4 v = *(const float4*)&X[(size_t)(b0 + b) * (T_STEPS * D_IN) + d0];
        inv0[(d0 + 0) * BC + b] = v.x; inv0[(d0 + 1) * BC + b] = v.y;
        inv0[(d0 + 2) * BC + b] = v.z; inv0[(d0 + 3) * BC + b] = v.w;
    }
    __syncthreads();

    float4 xr = {0.f, 0.f, 0.f, 0.f};

    for (int tau = 0; tau < T_STEPS + 5; ++tau) {
        // ================= G phase: all gemms concurrent =================
        if (tid < 96) {
            if (tau < 512)              gemm_sec<16, 4, 4>(wr, bs, tid,       inv0,    gate, 0);
        } else if (tid < 192) {
            if (tau < 512)              gemm_sec< 8, 4, 0>(wr, bs, tid - 96,  hbuf[0], gate, 96);
        } else if (tid < 240) {
            if (tau >= 4 && tau <= 515) gemm_sec<16, 2, 0>(wr, bs, tid - 192, hbuf[4], gate, 528);
        } else if (tid < 288) {
            if (tau >= 1 && tau <= 512) gemm_sec< 8, 4, 0>(wr, bs, tid - 240, hbuf[0], gate, 192);
        } else if (tid < 312) {
            if (tau >= 1 && tau <= 512) gemm_sec< 8, 2, 0>(wr, bs, tid - 288, hbuf[1], gate, 240);
        } else if (tid < 336) {
            if (tau >= 3 && tau <= 514) gemm_sec< 8, 2, 0>(wr, bs, tid - 312, hbuf[3], gate, 384);
        } else if (tid < 384) {
            if (tau >= 4 && tau <= 515) gemm_sec< 8, 2, 0>(wr, bs, tid - 336, hbuf[3], gate, 432);
        } else if (tid < 448) {
            if (tau >= 5)               out_sec< 8, 4>(wr, bs, tid - 384, hbuf[4],
                                            out + ((size_t)b0 * T_STEPS + (tau - 5)) * 64);
        } else if (tid < 460) {
            if (tau >= 2 && tau <= 513) gemm_sec< 8, 2, 0>(wr, bs, tid - 448, hbuf[1], gate, 288);
        } else if (tid < 466) {
            if (tau >= 2 && tau <= 513) gemm_sec< 8, 1, 0>(wr, bs, tid - 460, hbuf[2], gate, 312);
        } else if (tid < 478) {
            if (tau >= 3 && tau <= 514) gemm_sec< 8, 1, 0>(wr, bs, tid - 466, hbuf[2], gate, 336);
        } else if (tid >= 480) {
            if (tau + 1 < T_STEPS) {    // prefetch x(tau+1) into registers
                const int e = tid - 480, b = e >> 4, d0 = (e & 15) << 2;
                xr = *(const float4*)&X[((size_t)(b0 + b) * T_STEPS + (tau + 1)) * D_IN + d0];
            }
        }
        __syncthreads();
        // ================= U phase: all layer updates concurrent =================
        if (tid < 64) {
            if (tau < 512)              upd(32, hbuf[0], tid,       gate, 0,   96);
        } else if (tid < 96) {
            if (tau >= 1 && tau <= 512) upd(16, hbuf[1], tid - 64,  gate, 192, 240);
        } else if (tid < 112) {
            if (tau >= 2 && tau <= 513) upd(8,  hbuf[2], tid - 96,  gate, 288, 312);
        } else if (tid < 144) {
            if (tau >= 3 && tau <= 514) upd(16, hbuf[3], tid - 112, gate, 336, 384);
        } else if (tid < 208) {
            if (tau >= 4 && tau <= 515) upd(32, hbuf[4], tid - 144, gate, 432, 528);
        } else if (tid >= 480) {
            if (tau + 1 < T_STEPS) {    // commit x(tau+1) to LDS
                const int e = tid - 480, b = e >> 4, d0 = (e & 15) << 2;
                inv0[(d0 + 0) * BC + b] = xr.x; inv0[(d0 + 1) * BC + b] = xr.y;
                inv0[(d0 + 2) * BC + b] = xr.z; inv0[(d0 + 3) * BC + b] = xr.w;
            }
        }
        __syncthreads();
    }
}

extern "C" void kernel_launch(void* const* d_in, const int* in_sizes, int n_in,
                              void* d_out, int out_size, void* d_ws, size_t ws_size,
                              hipStream_t stream)
{
    const float* X = (const float*)d_in[0];
    const float* wih[5]; const float* whh[5]; const float* bih[5]; const float* bhh[5];
    for (int l = 0; l < 5; ++l) {
        wih[l] = (const float*)d_in[1 + 4 * l];
        whh[l] = (const float*)d_in[2 + 4 * l];
        bih[l] = (const float*)d_in[3 + 4 * l];
        bhh[l] = (const float*)d_in[4 + 4 * l];
    }
    const float* wout = (const float*)d_in[21];
    const float* bout = (const float*)d_in[22];

    gru_kernel<<<1024 / BC, BLOCK, 0, stream>>>(
        X,
        wih[0], whh[0], bih[0], bhh[0],
        wih[1], whh[1], bih[1], bhh[1],
        wih[2], whh[2], bih[2], bhh[2],
        wih[3], whh[3], bih[3], bhh[3],
        wih[4], whh[4], bih[4], bhh[4],
        wout, bout,
        (float*)d_out);
}